// Round 2
// 410.536 us; speedup vs baseline: 1.0347x; 1.0347x over previous
//
#include <hip/hip_runtime.h>

// RoPE2D: x (T=8192, 2, D=4096) fp32 -> out same shape.
// angle(t) = t * 2*pi/10; since 10*theta == 2*pi exactly, only t % 10 matters.
// 10 distinct (cos, sin) pairs -> compile-time __constant__ table, indexed by a
// SCALAR (blockIdx-derived) k so c/s live in SGPRs (zero per-lane trig VALU).
// Pure streaming kernel: nontemporal float4 loads/stores.

typedef float v4f __attribute__((ext_vector_type(4)));

// cos(k * 36 deg), sin(k * 36 deg), double-precision values rounded to float.
__constant__ float C_TAB[10] = {
     1.0f,                    0.8090169943749474241f,  0.3090169943749474241f,
    -0.3090169943749474241f, -0.8090169943749474241f, -1.0f,
    -0.8090169943749474241f, -0.3090169943749474241f,  0.3090169943749474241f,
     0.8090169943749474241f
};
__constant__ float S_TAB[10] = {
     0.0f,                    0.5877852522924731292f,  0.9510565162951535721f,
     0.9510565162951535721f,  0.5877852522924731292f,  0.0f,
    -0.5877852522924731292f, -0.9510565162951535721f, -0.9510565162951535721f,
    -0.5877852522924731292f
};

__global__ __launch_bounds__(256) void rope2d_kernel(
    const v4f* __restrict__ x, v4f* __restrict__ out) {
    // Each half-row is 1024 float4; one block of 256 covers a quarter of it,
    // so 4 blocks per t. t and k are block-uniform -> pure scalar (SGPR) ops.
    const unsigned b = blockIdx.x;
    const unsigned t = b >> 2;                         // row index (scalar)
    const unsigned j = ((b & 3u) << 8) | threadIdx.x;  // float4 col in half-row
    const unsigned k = t - (t / 10u) * 10u;            // t % 10, scalar magic-mul

    const float c = C_TAB[k];                          // s_load, broadcast
    const float s = S_TAB[k];

    const unsigned base = t << 11;                     // 2048 float4 per t
    const v4f a = __builtin_nontemporal_load(&x[base + j]);          // x[t,0,..]
    const v4f v = __builtin_nontemporal_load(&x[base + 1024 + j]);   // x[t,1,..]

    v4f o0, o1;
    o0 = c * a - s * v;
    o1 = s * a + c * v;

    __builtin_nontemporal_store(o0, &out[base + j]);
    __builtin_nontemporal_store(o1, &out[base + 1024 + j]);
}

extern "C" void kernel_launch(void* const* d_in, const int* in_sizes, int n_in,
                              void* d_out, int out_size, void* d_ws, size_t ws_size,
                              hipStream_t stream) {
    const v4f* x = (const v4f*)d_in[0];
    v4f* out = (v4f*)d_out;

    // out_size = T*2*D elements; float4-pairs = out_size/8; 256 pairs per block.
    const int total = (out_size / 2) / 4;              // = T * 1024
    const int block = 256;
    const int grid = total / block;                    // = T * 4 (exact multiple)

    rope2d_kernel<<<grid, block, 0, stream>>>(x, out);
}